// Round 4
// baseline (549.318 us; speedup 1.0000x reference)
//
#include <hip/hip_runtime.h>

typedef _Float16 f16;
typedef _Float16 f16x4 __attribute__((ext_vector_type(4)));
typedef _Float16 f16x8 __attribute__((ext_vector_type(8)));
typedef float f32x4 __attribute__((ext_vector_type(4)));
typedef int i32x4 __attribute__((ext_vector_type(4)));

#define ALPHA 0.2f
#define NN 8192
#define DD 256
#define INVLN2 1.44269504088896f

#define MFMA16(a, b, c) __builtin_amdgcn_mfma_f32_16x16x32_f16(a, b, c, 0, 0, 0)

// ---------------- K1: Wh = h @ W (f32), plus WhT in fp16 ----------------
// grid 256 blocks x 256 thr; block: 32 rows x 256 cols, K=256.
__global__ __launch_bounds__(256) void k1_gemm(const float* __restrict__ h,
                                               const float* __restrict__ W,
                                               float* __restrict__ Wh,
                                               f16* __restrict__ WhT) {
    __shared__ float h_lds[32][256];
    const int t  = threadIdx.x;
    const int i0 = blockIdx.x * 32;

    #pragma unroll
    for (int p = 0; p < 8; ++p) {
        int idx = p * 256 + t;
        int r = idx >> 6;
        int c = (idx & 63) << 2;
        *(float4*)&h_lds[r][c] = *(const float4*)&h[(size_t)(i0 + r) * DD + c];
    }
    __syncthreads();

    const int c0 = (t & 63) << 2;
    const int r0 = (t >> 6) << 3;
    float acc[8][4];
    #pragma unroll
    for (int r = 0; r < 8; ++r)
        #pragma unroll
        for (int c = 0; c < 4; ++c) acc[r][c] = 0.f;

    for (int k = 0; k < DD; ++k) {
        float4 w4 = *(const float4*)&W[k * DD + c0];
        #pragma unroll
        for (int r = 0; r < 8; ++r) {
            float hv = h_lds[r0 + r][k];
            acc[r][0] = fmaf(hv, w4.x, acc[r][0]);
            acc[r][1] = fmaf(hv, w4.y, acc[r][1]);
            acc[r][2] = fmaf(hv, w4.z, acc[r][2]);
            acc[r][3] = fmaf(hv, w4.w, acc[r][3]);
        }
    }

    #pragma unroll
    for (int r = 0; r < 8; ++r) {
        float4 v; v.x = acc[r][0]; v.y = acc[r][1]; v.z = acc[r][2]; v.w = acc[r][3];
        *(float4*)&Wh[(size_t)(i0 + r0 + r) * DD + c0] = v;
    }
    #pragma unroll
    for (int c = 0; c < 4; ++c) {
        f16x8 v;
        #pragma unroll
        for (int r = 0; r < 8; ++r) v[r] = (f16)acc[r][c];
        *(f16x8*)&WhT[(size_t)(c0 + c) * NN + i0 + r0] = v;
    }
}

// ---------------- K2: Wh1/Wh2 row dots (pre-scaled by 1/ln2), global max ----------------
__global__ __launch_bounds__(256) void k2_rowdot(const float* __restrict__ Wh,
                                                 const float* __restrict__ a,
                                                 float* __restrict__ Wh1,
                                                 float* __restrict__ Wh2,
                                                 unsigned* __restrict__ maxkey) {
    const int lane = threadIdx.x & 63;
    const int wave = threadIdx.x >> 6;
    const int i = blockIdx.x * 4 + wave;

    float4 v  = *(const float4*)&Wh[(size_t)i * DD + lane * 4];
    float4 a1 = *(const float4*)&a[lane * 4];
    float4 a2 = *(const float4*)&a[DD + lane * 4];
    float s1 = v.x * a1.x + v.y * a1.y + v.z * a1.z + v.w * a1.w;
    float s2 = v.x * a2.x + v.y * a2.y + v.z * a2.z + v.w * a2.w;
    #pragma unroll
    for (int off = 32; off; off >>= 1) {
        s1 += __shfl_down(s1, off);
        s2 += __shfl_down(s2, off);
    }
    if (lane == 0) {
        s1 *= INVLN2;
        s2 *= INVLN2;
        Wh1[i] = s1;
        Wh2[i] = s2;
        unsigned u = __float_as_uint(s2);
        u = (u & 0x80000000u) ? ~u : (u | 0x80000000u);
        atomicMax(maxkey, u);
    }
}

// ---------------- K3: fused masked softmax + PV, LDS-shared P ----------------
// grid 1024 = js(8, outer) x i-tile(128, inner). 256 thr = 4 waves.
// Block: 64 out rows, j-range 1024 (8 steps of 128). Wave w owns n in [w*64, w*64+64).
// Phase A: all threads build P[64][128] f16 -> swizzled LDS (double-buffered).
// Phase B: per wave, A-frags (WhT) from global, B-frags (P) from LDS, 64 MFMA/step.
// Cross-js reduction: f32 atomicAdd into zeroed D + S.
__global__ __launch_bounds__(256, 3) void k3_attn(const int* __restrict__ adj,
                                                  const f16* __restrict__ WhT,
                                                  const float* __restrict__ Wh1,
                                                  const float* __restrict__ Wh2,
                                                  const unsigned* __restrict__ maxkey,
                                                  float* __restrict__ D,
                                                  float* __restrict__ S) {
    __shared__ __align__(16) unsigned char p_lds[2][64 * 256];   // 2 x 16 KB

    const int t    = threadIdx.x;
    const int lane = t & 63;
    const int w    = t >> 6;
    const int bid  = blockIdx.x;
    const int i0   = (bid & 127) * 64;
    const int js   = bid >> 7;
    const int jb0  = js * 1024;

    unsigned mk = *maxkey;
    const float maxW2 = __uint_as_float((mk & 0x80000000u) ? (mk & 0x7fffffffu) : ~mk);

    // phase-A mapping: thread -> row (0..63), j-chunk jq (32 cols)
    const int row = t >> 2;
    const int jq  = (t & 3) << 5;
    const float wh1r = Wh1[i0 + row];
    float tm = wh1r + maxW2;
    const float m_r = fmaxf(tm, ALPHA * tm);

    const int* adjRow = adj + (size_t)(i0 + row) * NN;
    const int pwbase = row << 8;             // byte base of row in P_lds
    const int rsw = (row & 15) << 4;         // write-side XOR swizzle

    // phase-B mapping
    const int r  = lane & 15;
    const int g8 = (lane >> 4) << 3;
    const int nw = w << 6;                   // wave's n base
    const int bsw_base = g8 << 1;            // (lane>>4)*16 byte offset
    const int rxor = r << 4;                 // read-side XOR swizzle (row&15 == r)

    f32x4 acc[4][4];
    #pragma unroll
    for (int nt = 0; nt < 4; ++nt)
        #pragma unroll
        for (int it = 0; it < 4; ++it) acc[nt][it] = (f32x4){0.f, 0.f, 0.f, 0.f};
    float s_acc = 0.f;

    for (int s = 0; s < 8; ++s) {
        const int jb = jb0 + (s << 7);
        const int sel = s & 1;

        // ---- phase A: P tile -> LDS ----
        #pragma unroll
        for (int e = 0; e < 8; ++e) {
            i32x4 av  = __builtin_nontemporal_load((const i32x4*)(adjRow + jb + jq + e * 4));
            float4 w2 = *(const float4*)&Wh2[jb + jq + e * 4];
            float e0 = wh1r + w2.x; e0 = fmaxf(e0, ALPHA * e0);
            float e1 = wh1r + w2.y; e1 = fmaxf(e1, ALPHA * e1);
            float e2 = wh1r + w2.z; e2 = fmaxf(e2, ALPHA * e2);
            float e3 = wh1r + w2.w; e3 = fmaxf(e3, ALPHA * e3);
            float p0 = (av.x > 0) ? exp2f(e0 - m_r) : 0.f;
            float p1 = (av.y > 0) ? exp2f(e1 - m_r) : 0.f;
            float p2 = (av.z > 0) ? exp2f(e2 - m_r) : 0.f;
            float p3 = (av.w > 0) ? exp2f(e3 - m_r) : 0.f;
            s_acc += (p0 + p1) + (p2 + p3);
            f16x4 pk; pk[0] = (f16)p0; pk[1] = (f16)p1; pk[2] = (f16)p2; pk[3] = (f16)p3;
            *(f16x4*)&p_lds[sel][pwbase + (((jq << 1) + (e << 3)) ^ rsw)] = pk;
        }
        __syncthreads();

        // ---- phase B: MFMA over K=128 ----
        const f16* wbase = WhT + jb + g8;
        #pragma unroll
        for (int kt = 0; kt < 4; ++kt) {
            f16x8 A0 = *(const f16x8*)(wbase + (size_t)(nw +      r) * NN + kt * 32);
            f16x8 A1 = *(const f16x8*)(wbase + (size_t)(nw + 16 + r) * NN + kt * 32);
            f16x8 A2 = *(const f16x8*)(wbase + (size_t)(nw + 32 + r) * NN + kt * 32);
            f16x8 A3 = *(const f16x8*)(wbase + (size_t)(nw + 48 + r) * NN + kt * 32);
            const int cb = (kt * 64 + bsw_base) ^ rxor;
            f16x8 B0 = *(const f16x8*)&p_lds[sel][(0 * 16 + r) * 256 + cb];
            f16x8 B1 = *(const f16x8*)&p_lds[sel][(1 * 16 + r) * 256 + cb];
            f16x8 B2 = *(const f16x8*)&p_lds[sel][(2 * 16 + r) * 256 + cb];
            f16x8 B3 = *(const f16x8*)&p_lds[sel][(3 * 16 + r) * 256 + cb];
            acc[0][0] = MFMA16(A0, B0, acc[0][0]);
            acc[0][1] = MFMA16(A0, B1, acc[0][1]);
            acc[0][2] = MFMA16(A0, B2, acc[0][2]);
            acc[0][3] = MFMA16(A0, B3, acc[0][3]);
            acc[1][0] = MFMA16(A1, B0, acc[1][0]);
            acc[1][1] = MFMA16(A1, B1, acc[1][1]);
            acc[1][2] = MFMA16(A1, B2, acc[1][2]);
            acc[1][3] = MFMA16(A1, B3, acc[1][3]);
            acc[2][0] = MFMA16(A2, B0, acc[2][0]);
            acc[2][1] = MFMA16(A2, B1, acc[2][1]);
            acc[2][2] = MFMA16(A2, B2, acc[2][2]);
            acc[2][3] = MFMA16(A2, B3, acc[2][3]);
            acc[3][0] = MFMA16(A3, B0, acc[3][0]);
            acc[3][1] = MFMA16(A3, B1, acc[3][1]);
            acc[3][2] = MFMA16(A3, B2, acc[3][2]);
            acc[3][3] = MFMA16(A3, B3, acc[3][3]);
        }
    }

    // ---- row-sum: 4 threads per row are consecutive lanes ----
    s_acc += __shfl_xor(s_acc, 1);
    s_acc += __shfl_xor(s_acc, 2);
    if ((t & 3) == 0) atomicAdd(&S[i0 + row], s_acc);

    // ---- accumulate D^T fragments: D[i][n] += acc ----
    #pragma unroll
    for (int nt = 0; nt < 4; ++nt) {
        #pragma unroll
        for (int it = 0; it < 4; ++it) {
            #pragma unroll
            for (int q = 0; q < 4; ++q) {
                int n = nw + nt * 16 + (lane >> 4) * 4 + q;   // C/D row = n
                int i = i0 + it * 16 + r;                      // C/D col = i
                atomicAdd(&D[(size_t)i * DD + n], acc[nt][it][q]);
            }
        }
    }
}

// ---------------- K4: normalize + ELU ----------------
__global__ __launch_bounds__(256) void k4_finish(const float* __restrict__ D,
                                                 const float* __restrict__ S,
                                                 float* __restrict__ out) {
    const int g   = blockIdx.x * 256 + threadIdx.x;   // 0..524287
    const int row = g >> 6;
    const int c4  = (g & 63) << 2;
    const float inv = 1.0f / S[row];
    f32x4 v = *(const f32x4*)&D[((size_t)row << 8) + c4];
    f32x4 o;
    #pragma unroll
    for (int q = 0; q < 4; ++q) {
        float x = v[q] * inv;
        o[q] = (x > 0.f) ? x : (__expf(x) - 1.f);
    }
    *(f32x4*)&out[((size_t)row << 8) + c4] = o;
}

extern "C" void kernel_launch(void* const* d_in, const int* in_sizes, int n_in,
                              void* d_out, int out_size, void* d_ws, size_t ws_size,
                              hipStream_t stream) {
    const float* h   = (const float*)d_in[0];
    const int*   adj = (const int*)d_in[1];
    const float* W   = (const float*)d_in[2];
    const float* a   = (const float*)d_in[3];
    float* out = (float*)d_out;

    char* ws = (char*)d_ws;
    float*    Wh     = (float*)ws;                     // 8 MB
    f16*      WhT    = (f16*)(ws + 8388608);           // 4 MB
    float*    Wh1    = (float*)(ws + 12582912);        // 32 KB
    float*    Wh2    = (float*)(ws + 12615680);        // 32 KB
    unsigned* maxkey = (unsigned*)(ws + 12648448);     // 4 B (pad 256)
    float*    S      = (float*)(ws + 12648704);        // 32 KB
    float*    D      = (float*)(ws + 12681472);        // 8 MB

    // zero maxkey + S + D in one async memset (region is contiguous)
    hipMemsetAsync(ws + 12648448, 0, 256 + 32768 + 8388608, stream);
    k1_gemm<<<dim3(256), dim3(256), 0, stream>>>(h, W, Wh, WhT);
    k2_rowdot<<<dim3(2048), dim3(256), 0, stream>>>(Wh, a, Wh1, Wh2, maxkey);
    k3_attn<<<dim3(1024), dim3(256), 0, stream>>>(adj, WhT, Wh1, Wh2, maxkey, D, S);
    k4_finish<<<dim3(2048), dim3(256), 0, stream>>>(D, S, out);
}

// Round 6
// 218.141 us; speedup vs baseline: 2.5182x; 2.5182x over previous
//
#include <hip/hip_runtime.h>

typedef _Float16 f16;
typedef _Float16 f16x4 __attribute__((ext_vector_type(4)));
typedef _Float16 f16x8 __attribute__((ext_vector_type(8)));
typedef float f32x4 __attribute__((ext_vector_type(4)));
typedef int i32x4 __attribute__((ext_vector_type(4)));

#define ALPHA 0.2f
#define NN 8192
#define DD 256
#define INVLN2 1.44269504088896f
#define MFMA16(a, b, c) __builtin_amdgcn_mfma_f32_16x16x32_f16(a, b, c, 0, 0, 0)

// ---------------- K0: prep — WT=f16(W^T), r1=W@a1*invln2, r2=W@a2*invln2 ----------
// grid 18: blocks 0..15 transpose a 16-k slice of W; blocks 16,17 compute r1/r2.
__global__ __launch_bounds__(256) void k0_prep(const float* __restrict__ W,
                                               const float* __restrict__ a,
                                               f16* __restrict__ WT,
                                               float* __restrict__ r1,
                                               float* __restrict__ r2) {
    const int b = blockIdx.x;
    const int t = threadIdx.x;
    if (b < 16) {
        __shared__ f16 tl[16][256];
        const int k0 = b * 16;
        const int kr = t >> 4, cb = (t & 15) << 4;
        #pragma unroll
        for (int p = 0; p < 4; ++p) {
            float4 v = *(const float4*)&W[(k0 + kr) * DD + cb + p * 4];
            tl[kr][cb + p * 4 + 0] = (f16)v.x;
            tl[kr][cb + p * 4 + 1] = (f16)v.y;
            tl[kr][cb + p * 4 + 2] = (f16)v.z;
            tl[kr][cb + p * 4 + 3] = (f16)v.w;
        }
        __syncthreads();
        f16 outv[16];
        #pragma unroll
        for (int q = 0; q < 16; ++q) outv[q] = tl[q][t];
        *(f16x8*)&WT[t * DD + k0]     = *(f16x8*)&outv[0];
        *(f16x8*)&WT[t * DD + k0 + 8] = *(f16x8*)&outv[8];
    } else {
        __shared__ float al[256];
        al[t] = a[(b - 16) * DD + t];
        __syncthreads();
        // r[t] = dot(W[t][:], a)  -- fold over W's SECOND index (d_out)
        float s = 0.f;
        for (int k = 0; k < DD; ++k) s = fmaf(W[t * DD + k], al[k], s);
        float* rr = (b == 16) ? r1 : r2;
        rr[t] = s * INVLN2;
    }
}

// ---------------- K1: WhT = f16(h@W)^T via MFMA; wave0 also Wh1/Wh2 + maxkey ------
// grid 512 x 256 thr (4 waves). Block: 16 i-rows, full n=256 (wave w: n=w*64..+64).
__global__ __launch_bounds__(256) void k1_gemm(const float* __restrict__ h,
                                               const f16* __restrict__ WT,
                                               const float* __restrict__ r1,
                                               const float* __restrict__ r2,
                                               f16* __restrict__ WhT,
                                               float* __restrict__ Wh1,
                                               float* __restrict__ Wh2,
                                               unsigned* __restrict__ maxkey) {
    const int t    = threadIdx.x;
    const int lane = t & 63;
    const int w    = t >> 6;
    const int i0   = blockIdx.x * 16;
    const int r    = lane & 15;
    const int hi   = lane >> 4;
    const int nbase = w * 64;

    f32x4 acc[4];
    #pragma unroll
    for (int nc = 0; nc < 4; ++nc) acc[nc] = (f32x4){0.f, 0.f, 0.f, 0.f};
    float s1 = 0.f, s2 = 0.f;

    const float* hrow = h + (size_t)(i0 + r) * DD;
    #pragma unroll
    for (int kt = 0; kt < 8; ++kt) {
        const int kb = kt * 32 + hi * 8;
        float4 h0 = *(const float4*)&hrow[kb];
        float4 h1 = *(const float4*)&hrow[kb + 4];
        f16x8 af;
        af[0] = (f16)h0.x; af[1] = (f16)h0.y; af[2] = (f16)h0.z; af[3] = (f16)h0.w;
        af[4] = (f16)h1.x; af[5] = (f16)h1.y; af[6] = (f16)h1.z; af[7] = (f16)h1.w;
        if (w == 0) {
            float4 ra0 = *(const float4*)&r1[kb];
            float4 ra1 = *(const float4*)&r1[kb + 4];
            float4 rb0 = *(const float4*)&r2[kb];
            float4 rb1 = *(const float4*)&r2[kb + 4];
            s1 += h0.x * ra0.x + h0.y * ra0.y + h0.z * ra0.z + h0.w * ra0.w
                + h1.x * ra1.x + h1.y * ra1.y + h1.z * ra1.z + h1.w * ra1.w;
            s2 += h0.x * rb0.x + h0.y * rb0.y + h0.z * rb0.z + h0.w * rb0.w
                + h1.x * rb1.x + h1.y * rb1.y + h1.z * rb1.z + h1.w * rb1.w;
        }
        #pragma unroll
        for (int nc = 0; nc < 4; ++nc) {
            f16x8 bf = *(const f16x8*)&WT[(nbase + nc * 16 + r) * DD + kb];
            acc[nc] = MFMA16(af, bf, acc[nc]);
        }
    }
    #pragma unroll
    for (int nc = 0; nc < 4; ++nc) {
        f16x4 o;
        o[0] = (f16)acc[nc][0]; o[1] = (f16)acc[nc][1];
        o[2] = (f16)acc[nc][2]; o[3] = (f16)acc[nc][3];
        *(f16x4*)&WhT[(size_t)(nbase + nc * 16 + r) * NN + i0 + hi * 4] = o;
    }
    if (w == 0) {
        s1 += __shfl_xor(s1, 16); s1 += __shfl_xor(s1, 32);
        s2 += __shfl_xor(s2, 16); s2 += __shfl_xor(s2, 32);
        if (lane < 16) {
            Wh1[i0 + lane] = s1;
            Wh2[i0 + lane] = s2;
            unsigned u = __float_as_uint(s2);
            u = (u & 0x80000000u) ? ~u : (u | 0x80000000u);
            atomicMax(maxkey, u);
        }
    }
}

// ---------------- K3: fused masked softmax + PV ----------------
// grid = js_n*256 blocks x 256 thr (4 waves). Block: 32 i-rows, j-range NN/js_n,
// steps of 64 j. P dbuf in swizzled LDS (8KB). Wave w: n in [w*64, w*64+64).
// Partial D written to private slab js (plain nt stores); S via atomicAdd.
__device__ __forceinline__ f16x8 pcomp8(i32x4 a0, i32x4 a1, float4 q0, float4 q1,
                                        float wh1r, float m_r, float& sacc) {
    float p[8];
    float e;
    e = wh1r + q0.x; e = fmaxf(e, ALPHA * e); p[0] = (a0.x > 0) ? exp2f(e - m_r) : 0.f;
    e = wh1r + q0.y; e = fmaxf(e, ALPHA * e); p[1] = (a0.y > 0) ? exp2f(e - m_r) : 0.f;
    e = wh1r + q0.z; e = fmaxf(e, ALPHA * e); p[2] = (a0.z > 0) ? exp2f(e - m_r) : 0.f;
    e = wh1r + q0.w; e = fmaxf(e, ALPHA * e); p[3] = (a0.w > 0) ? exp2f(e - m_r) : 0.f;
    e = wh1r + q1.x; e = fmaxf(e, ALPHA * e); p[4] = (a1.x > 0) ? exp2f(e - m_r) : 0.f;
    e = wh1r + q1.y; e = fmaxf(e, ALPHA * e); p[5] = (a1.y > 0) ? exp2f(e - m_r) : 0.f;
    e = wh1r + q1.z; e = fmaxf(e, ALPHA * e); p[6] = (a1.z > 0) ? exp2f(e - m_r) : 0.f;
    e = wh1r + q1.w; e = fmaxf(e, ALPHA * e); p[7] = (a1.w > 0) ? exp2f(e - m_r) : 0.f;
    sacc += ((p[0] + p[1]) + (p[2] + p[3])) + ((p[4] + p[5]) + (p[6] + p[7]));
    f16x8 pk;
    pk[0] = (f16)p[0]; pk[1] = (f16)p[1]; pk[2] = (f16)p[2]; pk[3] = (f16)p[3];
    pk[4] = (f16)p[4]; pk[5] = (f16)p[5]; pk[6] = (f16)p[6]; pk[7] = (f16)p[7];
    return pk;
}

__global__ __launch_bounds__(256, 4) void k3_attn(const int* __restrict__ adj,
                                                  const f16* __restrict__ WhT,
                                                  const float* __restrict__ Wh1,
                                                  const float* __restrict__ Wh2,
                                                  const unsigned* __restrict__ maxkey,
                                                  float* __restrict__ D,
                                                  float* __restrict__ S,
                                                  int jrange) {
    __shared__ __align__(16) unsigned char p_lds[2][32 * 128];   // 8 KB

    const int t     = threadIdx.x;
    const int lane  = t & 63;
    const int w     = t >> 6;
    const int itile = blockIdx.x & 255;
    const int js    = blockIdx.x >> 8;
    const int i0    = itile * 32;
    const int jb0   = js * jrange;
    const int ns    = jrange >> 6;

    unsigned mk = *maxkey;
    const float maxW2 = __uint_as_float((mk & 0x80000000u) ? (mk & 0x7fffffffu) : ~mk);

    // phase-A role: thread -> row (0..31), j-chunk jc (8 j's)
    const int row = t >> 3;
    const int jc  = t & 7;
    const float wh1r = Wh1[i0 + row];
    float tm = wh1r + maxW2;
    const float m_r = fmaxf(tm, ALPHA * tm);
    const int*   aRow = adj + (size_t)(i0 + row) * NN + jc * 8;
    const float* w2p  = Wh2 + jc * 8;
    const int pwb = row * 128 + ((jc * 16) ^ ((row & 7) << 4));

    // phase-B role
    const int r     = lane & 15;
    const int hi    = lane >> 4;
    const int nbase = w * 64;
    const int hi16  = hi * 16;
    const int rsw   = (r & 7) << 4;

    f32x4 acc[2][4];
    #pragma unroll
    for (int ic = 0; ic < 2; ++ic)
        #pragma unroll
        for (int nc = 0; nc < 4; ++nc) acc[ic][nc] = (f32x4){0.f, 0.f, 0.f, 0.f};
    float sacc = 0.f;

    // prologue: step 0 P -> lds[0]
    {
        i32x4 a0 = __builtin_nontemporal_load((const i32x4*)(aRow + jb0));
        i32x4 a1 = __builtin_nontemporal_load((const i32x4*)(aRow + jb0 + 4));
        float4 q0 = *(const float4*)(w2p + jb0);
        float4 q1 = *(const float4*)(w2p + jb0 + 4);
        f16x8 pk = pcomp8(a0, a1, q0, q1, wh1r, m_r, sacc);
        *(f16x8*)&p_lds[0][pwb] = pk;
    }
    __syncthreads();

    for (int s = 0; s < ns; ++s) {
        const int sel = s & 1;
        // prefetch step s+1 (adj from HBM — issue before MFMA phase)
        i32x4 na0, na1;
        float4 nq0, nq1;
        const bool more = (s + 1 < ns);
        if (more) {
            const int jn = jb0 + ((s + 1) << 6);
            na0 = __builtin_nontemporal_load((const i32x4*)(aRow + jn));
            na1 = __builtin_nontemporal_load((const i32x4*)(aRow + jn + 4));
            nq0 = *(const float4*)(w2p + jn);
            nq1 = *(const float4*)(w2p + jn + 4);
        }

        // MFMA phase: K=64 (2 kt), A from LDS P, B from L2 WhT
        const f16* wb = WhT + (size_t)(nbase + r) * NN + jb0 + (s << 6) + hi * 8;
        #pragma unroll
        for (int kt = 0; kt < 2; ++kt) {
            const int kbyte = kt * 64 + hi16;
            f16x8 A0 = *(const f16x8*)&p_lds[sel][r * 128        + (kbyte ^ rsw)];
            f16x8 A1 = *(const f16x8*)&p_lds[sel][(16 + r) * 128 + (kbyte ^ rsw)];
            f16x8 B0 = *(const f16x8*)(wb + kt * 32);
            f16x8 B1 = *(const f16x8*)(wb + kt * 32 + 16 * NN);
            f16x8 B2 = *(const f16x8*)(wb + kt * 32 + 32 * NN);
            f16x8 B3 = *(const f16x8*)(wb + kt * 32 + 48 * NN);
            acc[0][0] = MFMA16(A0, B0, acc[0][0]);
            acc[0][1] = MFMA16(A0, B1, acc[0][1]);
            acc[0][2] = MFMA16(A0, B2, acc[0][2]);
            acc[0][3] = MFMA16(A0, B3, acc[0][3]);
            acc[1][0] = MFMA16(A1, B0, acc[1][0]);
            acc[1][1] = MFMA16(A1, B1, acc[1][1]);
            acc[1][2] = MFMA16(A1, B2, acc[1][2]);
            acc[1][3] = MFMA16(A1, B3, acc[1][3]);
        }

        // compute P for s+1 into the other buffer
        if (more) {
            f16x8 pk = pcomp8(na0, na1, nq0, nq1, wh1r, m_r, sacc);
            *(f16x8*)&p_lds[sel ^ 1][pwb] = pk;
        }
        __syncthreads();
    }

    // row-sum partial -> S (8 consecutive threads own one row)
    sacc += __shfl_xor(sacc, 1);
    sacc += __shfl_xor(sacc, 2);
    sacc += __shfl_xor(sacc, 4);
    if ((t & 7) == 0) atomicAdd(&S[i0 + row], sacc);

    // partial D -> private slab js (plain nontemporal stores)
    float* Dp = D + (size_t)js * NN * DD + (size_t)(i0 + hi * 4) * DD + nbase + r;
    #pragma unroll
    for (int ic = 0; ic < 2; ++ic)
        #pragma unroll
        for (int nc = 0; nc < 4; ++nc)
            #pragma unroll
            for (int q = 0; q < 4; ++q)
                __builtin_nontemporal_store(acc[ic][nc][q],
                                            Dp + (ic * 16 + q) * DD + nc * 16);
}

// ---------------- K4: sum slabs + normalize + ELU ----------------
__global__ __launch_bounds__(256) void k4_finish(const float* __restrict__ D,
                                                 const float* __restrict__ S,
                                                 float* __restrict__ out,
                                                 int nslab) {
    const int g   = blockIdx.x * 256 + threadIdx.x;
    const int rw  = g >> 6;
    const int c4  = (g & 63) << 2;
    const size_t off = ((size_t)rw << 8) + c4;
    f32x4 v = {0.f, 0.f, 0.f, 0.f};
    for (int s = 0; s < nslab; ++s)
        v += __builtin_nontemporal_load((const f32x4*)&D[off + (size_t)s * NN * DD]);
    const float inv = 1.0f / S[rw];
    f32x4 o;
    #pragma unroll
    for (int q = 0; q < 4; ++q) {
        float x = v[q] * inv;
        o[q] = (x > 0.f) ? x : (__expf(x) - 1.f);
    }
    *(f32x4*)&out[off] = o;
}

extern "C" void kernel_launch(void* const* d_in, const int* in_sizes, int n_in,
                              void* d_out, int out_size, void* d_ws, size_t ws_size,
                              hipStream_t stream) {
    const float* h   = (const float*)d_in[0];
    const int*   adj = (const int*)d_in[1];
    const float* W   = (const float*)d_in[2];
    const float* a   = (const float*)d_in[3];
    float* out = (float*)d_out;

    char* ws = (char*)d_ws;
    f16*      WT     = (f16*)ws;                        // 128 KB
    f16*      WhT    = (f16*)(ws + 131072);             // 4 MB
    float*    r1     = (float*)(ws + 4325376);          // 1 KB
    float*    r2     = (float*)(ws + 4326400);          // 1 KB
    float*    Wh1    = (float*)(ws + 4327424);          // 32 KB
    float*    Wh2    = (float*)(ws + 4360192);          // 32 KB
    unsigned* maxkey = (unsigned*)(ws + 4392960);       // 4 B (pad 256)
    float*    S      = (float*)(ws + 4393216);          // 32 KB
    float*    D      = (float*)(ws + 4425984);          // js_n x 8 MB

    const size_t base = 4425984;
    const size_t slab = (size_t)NN * DD * 4;
    int js_n = 1;
    if (ws_size >= base + 4 * slab) js_n = 4;
    else if (ws_size >= base + 2 * slab) js_n = 2;
    const int jrange = NN / js_n;

    hipMemsetAsync(ws + 4392960, 0, 256 + 32768, stream);
    k0_prep<<<dim3(18), dim3(256), 0, stream>>>(W, a, WT, r1, r2);
    k1_gemm<<<dim3(512), dim3(256), 0, stream>>>(h, WT, r1, r2, WhT, Wh1, Wh2, maxkey);
    k3_attn<<<dim3(js_n * 256), dim3(256), 0, stream>>>(adj, WhT, Wh1, Wh2, maxkey,
                                                        D, S, jrange);
    k4_finish<<<dim3(2048), dim3(256), 0, stream>>>(D, S, out, js_n);
}

// Round 7
// 143.621 us; speedup vs baseline: 3.8248x; 1.5189x over previous
//
#include <hip/hip_runtime.h>

typedef _Float16 f16;
typedef _Float16 f16x4 __attribute__((ext_vector_type(4)));
typedef _Float16 f16x8 __attribute__((ext_vector_type(8)));
typedef float f32x4 __attribute__((ext_vector_type(4)));
typedef int i32x4 __attribute__((ext_vector_type(4)));

#define ALPHA 0.2f
#define NN 8192
#define DD 256
#define INVLN2 1.44269504088896f
#define MFMA16(a, b, c) __builtin_amdgcn_mfma_f32_16x16x32_f16(a, b, c, 0, 0, 0)

// ---------------- K0: prep — WT=f16(W^T), r1=W@a1*invln2, r2=W@a2*invln2 ----------
__global__ __launch_bounds__(256) void k0_prep(const float* __restrict__ W,
                                               const float* __restrict__ a,
                                               f16* __restrict__ WT,
                                               float* __restrict__ r1,
                                               float* __restrict__ r2) {
    const int b = blockIdx.x;
    const int t = threadIdx.x;
    if (b < 16) {
        __shared__ f16 tl[16][256];
        const int k0 = b * 16;
        const int kr = t >> 4, cb = (t & 15) << 4;
        #pragma unroll
        for (int p = 0; p < 4; ++p) {
            float4 v = *(const float4*)&W[(k0 + kr) * DD + cb + p * 4];
            tl[kr][cb + p * 4 + 0] = (f16)v.x;
            tl[kr][cb + p * 4 + 1] = (f16)v.y;
            tl[kr][cb + p * 4 + 2] = (f16)v.z;
            tl[kr][cb + p * 4 + 3] = (f16)v.w;
        }
        __syncthreads();
        f16 outv[16];
        #pragma unroll
        for (int q = 0; q < 16; ++q) outv[q] = tl[q][t];
        *(f16x8*)&WT[t * DD + k0]     = *(f16x8*)&outv[0];
        *(f16x8*)&WT[t * DD + k0 + 8] = *(f16x8*)&outv[8];
    } else {
        __shared__ float al[256];
        al[t] = a[(b - 16) * DD + t];
        __syncthreads();
        float s = 0.f;
        for (int k = 0; k < DD; ++k) s = fmaf(W[t * DD + k], al[k], s);
        float* rr = (b == 16) ? r1 : r2;
        rr[t] = s * INVLN2;
    }
}

// ---------------- K1: WhT = f16(h@W)^T via MFMA; wave0 also Wh1/Wh2 + maxkey ------
__global__ __launch_bounds__(256) void k1_gemm(const float* __restrict__ h,
                                               const f16* __restrict__ WT,
                                               const float* __restrict__ r1,
                                               const float* __restrict__ r2,
                                               f16* __restrict__ WhT,
                                               float* __restrict__ Wh1,
                                               float* __restrict__ Wh2,
                                               unsigned* __restrict__ maxkey) {
    const int t    = threadIdx.x;
    const int lane = t & 63;
    const int w    = t >> 6;
    const int i0   = blockIdx.x * 16;
    const int r    = lane & 15;
    const int hi   = lane >> 4;
    const int nbase = w * 64;

    f32x4 acc[4];
    #pragma unroll
    for (int nc = 0; nc < 4; ++nc) acc[nc] = (f32x4){0.f, 0.f, 0.f, 0.f};
    float s1 = 0.f, s2 = 0.f;

    const float* hrow = h + (size_t)(i0 + r) * DD;
    #pragma unroll
    for (int kt = 0; kt < 8; ++kt) {
        const int kb = kt * 32 + hi * 8;
        float4 h0 = *(const float4*)&hrow[kb];
        float4 h1 = *(const float4*)&hrow[kb + 4];
        f16x8 af;
        af[0] = (f16)h0.x; af[1] = (f16)h0.y; af[2] = (f16)h0.z; af[3] = (f16)h0.w;
        af[4] = (f16)h1.x; af[5] = (f16)h1.y; af[6] = (f16)h1.z; af[7] = (f16)h1.w;
        if (w == 0) {
            float4 ra0 = *(const float4*)&r1[kb];
            float4 ra1 = *(const float4*)&r1[kb + 4];
            float4 rb0 = *(const float4*)&r2[kb];
            float4 rb1 = *(const float4*)&r2[kb + 4];
            s1 += h0.x * ra0.x + h0.y * ra0.y + h0.z * ra0.z + h0.w * ra0.w
                + h1.x * ra1.x + h1.y * ra1.y + h1.z * ra1.z + h1.w * ra1.w;
            s2 += h0.x * rb0.x + h0.y * rb0.y + h0.z * rb0.z + h0.w * rb0.w
                + h1.x * rb1.x + h1.y * rb1.y + h1.z * rb1.z + h1.w * rb1.w;
        }
        #pragma unroll
        for (int nc = 0; nc < 4; ++nc) {
            f16x8 bf = *(const f16x8*)&WT[(nbase + nc * 16 + r) * DD + kb];
            acc[nc] = MFMA16(af, bf, acc[nc]);
        }
    }
    #pragma unroll
    for (int nc = 0; nc < 4; ++nc) {
        f16x4 o;
        o[0] = (f16)acc[nc][0]; o[1] = (f16)acc[nc][1];
        o[2] = (f16)acc[nc][2]; o[3] = (f16)acc[nc][3];
        *(f16x4*)&WhT[(size_t)(nbase + nc * 16 + r) * NN + i0 + hi * 4] = o;
    }
    if (w == 0) {
        s1 += __shfl_xor(s1, 16); s1 += __shfl_xor(s1, 32);
        s2 += __shfl_xor(s2, 16); s2 += __shfl_xor(s2, 32);
        if (lane < 16) {
            Wh1[i0 + lane] = s1;
            Wh2[i0 + lane] = s2;
            unsigned u = __float_as_uint(s2);
            u = (u & 0x80000000u) ? ~u : (u | 0x80000000u);
            atomicMax(maxkey, u);
        }
    }
}

// ---------------- K3: fused masked softmax + PV, dbuf LDS GEMM ----------------
// grid = 128*js_n blocks x 512 thr (8 waves, 2x4 wave grid). Block: 64 i-rows,
// full n=256, j-steps of 64. LDS: WhT tile [256][64] 32KB + P tile [64][64] 8KB,
// both double-buffered (80KB), XOR-swizzled. Wave tile 32i x 64n (acc 2x4 f32x4).
// adj 2-step reg queue; WhT reg-staged issue-early/write-late. 1 barrier/step.
__device__ __forceinline__ f16x8 pcomp8(i32x4 a0, i32x4 a1, float4 q0, float4 q1,
                                        float wh1r, float m_r, float& sacc) {
    float p[8];
    float e;
    e = wh1r + q0.x; e = fmaxf(e, ALPHA * e); p[0] = (a0.x > 0) ? exp2f(e - m_r) : 0.f;
    e = wh1r + q0.y; e = fmaxf(e, ALPHA * e); p[1] = (a0.y > 0) ? exp2f(e - m_r) : 0.f;
    e = wh1r + q0.z; e = fmaxf(e, ALPHA * e); p[2] = (a0.z > 0) ? exp2f(e - m_r) : 0.f;
    e = wh1r + q0.w; e = fmaxf(e, ALPHA * e); p[3] = (a0.w > 0) ? exp2f(e - m_r) : 0.f;
    e = wh1r + q1.x; e = fmaxf(e, ALPHA * e); p[4] = (a1.x > 0) ? exp2f(e - m_r) : 0.f;
    e = wh1r + q1.y; e = fmaxf(e, ALPHA * e); p[5] = (a1.y > 0) ? exp2f(e - m_r) : 0.f;
    e = wh1r + q1.z; e = fmaxf(e, ALPHA * e); p[6] = (a1.z > 0) ? exp2f(e - m_r) : 0.f;
    e = wh1r + q1.w; e = fmaxf(e, ALPHA * e); p[7] = (a1.w > 0) ? exp2f(e - m_r) : 0.f;
    sacc += ((p[0] + p[1]) + (p[2] + p[3])) + ((p[4] + p[5]) + (p[6] + p[7]));
    f16x8 pk;
    pk[0] = (f16)p[0]; pk[1] = (f16)p[1]; pk[2] = (f16)p[2]; pk[3] = (f16)p[3];
    pk[4] = (f16)p[4]; pk[5] = (f16)p[5]; pk[6] = (f16)p[6]; pk[7] = (f16)p[7];
    return pk;
}

__global__ __launch_bounds__(512, 4) void k3_attn(const int* __restrict__ adj,
                                                  const f16* __restrict__ WhT,
                                                  const float* __restrict__ Wh1,
                                                  const float* __restrict__ Wh2,
                                                  const unsigned* __restrict__ maxkey,
                                                  float* __restrict__ D,
                                                  float* __restrict__ S,
                                                  int jrange) {
    __shared__ __align__(16) f16 wbuf[2][256 * 64];   // 2 x 32 KB
    __shared__ __align__(16) f16 pbuf[2][64 * 64];    // 2 x 8 KB

    const int t     = threadIdx.x;
    const int lane  = t & 63;
    const int w     = t >> 6;
    const int itile = blockIdx.x & 127;
    const int js    = blockIdx.x >> 7;
    const int i0    = itile * 64;
    const int jb0   = js * jrange;
    const int ns    = jrange >> 6;

    unsigned mk = *maxkey;
    const float maxW2 = __uint_as_float((mk & 0x80000000u) ? (mk & 0x7fffffffu) : ~mk);

    // P/adj role: row (0..63), seg jc (8 j's)
    const int row = t >> 3;
    const int jc  = t & 7;
    const float wh1r = Wh1[i0 + row];
    float tm = wh1r + maxW2;
    const float m_r = fmaxf(tm, ALPHA * tm);
    const int*   aRow = adj + (size_t)(i0 + row) * NN + jc * 8;
    const float* w2p  = Wh2 + jc * 8;
    const int pwb = row * 128 + ((jc ^ (row & 7)) << 4);   // byte offset in pbuf

    // WhT stage role: 4 rounds, round q: row n = q*64 + (t>>3), seg t&7
    const int sn   = t >> 3;
    const int swb0 = ((jc ^ (sn & 7)) << 4);               // same jc, row parity sn

    // MFMA role
    const int r   = lane & 15;
    const int hi  = lane >> 4;
    const int iw  = w >> 2;
    const int nw  = w & 3;
    const int rx  = (r & 7) << 4;

    f32x4 acc[2][4];
    #pragma unroll
    for (int ic = 0; ic < 2; ++ic)
        #pragma unroll
        for (int nc = 0; nc < 4; ++nc) acc[ic][nc] = (f32x4){0.f, 0.f, 0.f, 0.f};
    float sacc = 0.f;

    // ---- prologue: stage step 0, issue adj for step 1 ----
    {
        i32x4 a0 = __builtin_nontemporal_load((const i32x4*)(aRow + jb0));
        i32x4 a1 = __builtin_nontemporal_load((const i32x4*)(aRow + jb0 + 4));
        float4 q0 = *(const float4*)(w2p + jb0);
        float4 q1 = *(const float4*)(w2p + jb0 + 4);
        f16x8 pk = pcomp8(a0, a1, q0, q1, wh1r, m_r, sacc);
        *(f16x8*)((char*)pbuf[0] + pwb) = pk;
        #pragma unroll
        for (int q = 0; q < 4; ++q) {
            const int n = q * 64 + sn;
            i32x4 wv = *(const i32x4*)(WhT + (size_t)n * NN + jb0 + jc * 8);
            *(i32x4*)((char*)wbuf[0] + n * 128 + swb0) = wv;
        }
    }
    i32x4 aq0, aq1;
    float4 qq0, qq1;
    if (ns > 1) {
        aq0 = __builtin_nontemporal_load((const i32x4*)(aRow + jb0 + 64));
        aq1 = __builtin_nontemporal_load((const i32x4*)(aRow + jb0 + 68));
        qq0 = *(const float4*)(w2p + jb0 + 64);
        qq1 = *(const float4*)(w2p + jb0 + 68);
    }
    __syncthreads();

    for (int s = 0; s < ns; ++s) {
        const int sel = s & 1;
        const bool more = (s + 1 < ns);

        // issue WhT loads for s+1 (regs; write to LDS after MFMA phase)
        i32x4 wv0, wv1, wv2, wv3;
        if (more) {
            const f16* wsrc = WhT + jb0 + (s + 1) * 64 + jc * 8;
            wv0 = *(const i32x4*)(wsrc + (size_t)(0 * 64 + sn) * NN);
            wv1 = *(const i32x4*)(wsrc + (size_t)(1 * 64 + sn) * NN);
            wv2 = *(const i32x4*)(wsrc + (size_t)(2 * 64 + sn) * NN);
            wv3 = *(const i32x4*)(wsrc + (size_t)(3 * 64 + sn) * NN);
        }
        // consume adj queue (s+1), issue s+2
        i32x4 ca0 = aq0, ca1 = aq1;
        float4 cq0 = qq0, cq1 = qq1;
        if (s + 2 < ns) {
            const int jn = jb0 + (s + 2) * 64;
            aq0 = __builtin_nontemporal_load((const i32x4*)(aRow + jn));
            aq1 = __builtin_nontemporal_load((const i32x4*)(aRow + jn + 4));
            qq0 = *(const float4*)(w2p + jn);
            qq1 = *(const float4*)(w2p + jn + 4);
        }

        // ---- MFMA phase on buffers [sel] ----
        const char* pb = (const char*)pbuf[sel];
        const char* wb = (const char*)wbuf[sel];
        #pragma unroll
        for (int kt = 0; kt < 2; ++kt) {
            const int kb = ((kt * 4 + hi) << 4) ^ rx;
            f16x8 A0 = *(const f16x8*)(pb + (iw * 32 + r) * 128 + kb);
            f16x8 A1 = *(const f16x8*)(pb + (iw * 32 + 16 + r) * 128 + kb);
            f16x8 B0 = *(const f16x8*)(wb + (nw * 64 + r) * 128 + kb);
            f16x8 B1 = *(const f16x8*)(wb + (nw * 64 + 16 + r) * 128 + kb);
            f16x8 B2 = *(const f16x8*)(wb + (nw * 64 + 32 + r) * 128 + kb);
            f16x8 B3 = *(const f16x8*)(wb + (nw * 64 + 48 + r) * 128 + kb);
            acc[0][0] = MFMA16(A0, B0, acc[0][0]);
            acc[0][1] = MFMA16(A0, B1, acc[0][1]);
            acc[0][2] = MFMA16(A0, B2, acc[0][2]);
            acc[0][3] = MFMA16(A0, B3, acc[0][3]);
            acc[1][0] = MFMA16(A1, B0, acc[1][0]);
            acc[1][1] = MFMA16(A1, B1, acc[1][1]);
            acc[1][2] = MFMA16(A1, B2, acc[1][2]);
            acc[1][3] = MFMA16(A1, B3, acc[1][3]);
        }

        // ---- write step s+1 tiles into buffers [sel^1] ----
        if (more) {
            f16x8 pk = pcomp8(ca0, ca1, cq0, cq1, wh1r, m_r, sacc);
            char* pbn = (char*)pbuf[sel ^ 1];
            char* wbn = (char*)wbuf[sel ^ 1];
            *(f16x8*)(pbn + pwb) = pk;
            *(i32x4*)(wbn + (0 * 64 + sn) * 128 + swb0) = wv0;
            *(i32x4*)(wbn + (1 * 64 + sn) * 128 + swb0) = wv1;
            *(i32x4*)(wbn + (2 * 64 + sn) * 128 + swb0) = wv2;
            *(i32x4*)(wbn + (3 * 64 + sn) * 128 + swb0) = wv3;
        }
        __syncthreads();
    }

    // ---- row-sum partials -> S ----
    sacc += __shfl_xor(sacc, 1);
    sacc += __shfl_xor(sacc, 2);
    sacc += __shfl_xor(sacc, 4);
    if ((t & 7) == 0) atomicAdd(&S[i0 + row], sacc);

    // ---- partial D -> private slab js ----
    float* Dp = D + (size_t)js * NN * DD
                  + (size_t)(i0 + iw * 32 + hi * 4) * DD + nw * 64 + r;
    #pragma unroll
    for (int ic = 0; ic < 2; ++ic)
        #pragma unroll
        for (int nc = 0; nc < 4; ++nc)
            #pragma unroll
            for (int q = 0; q < 4; ++q)
                __builtin_nontemporal_store(acc[ic][nc][q],
                                            Dp + (size_t)(ic * 16 + q) * DD + nc * 16);
}

// ---------------- K4: sum slabs + normalize + ELU ----------------
__global__ __launch_bounds__(256) void k4_finish(const float* __restrict__ D,
                                                 const float* __restrict__ S,
                                                 float* __restrict__ out,
                                                 int nslab) {
    const int g   = blockIdx.x * 256 + threadIdx.x;
    const int rw  = g >> 6;
    const int c4  = (g & 63) << 2;
    const size_t off = ((size_t)rw << 8) + c4;
    f32x4 v = {0.f, 0.f, 0.f, 0.f};
    for (int s = 0; s < nslab; ++s)
        v += __builtin_nontemporal_load((const f32x4*)&D[off + (size_t)s * NN * DD]);
    const float inv = 1.0f / S[rw];
    f32x4 o;
    #pragma unroll
    for (int q = 0; q < 4; ++q) {
        float x = v[q] * inv;
        o[q] = (x > 0.f) ? x : (__expf(x) - 1.f);
    }
    *(f32x4*)&out[off] = o;
}

extern "C" void kernel_launch(void* const* d_in, const int* in_sizes, int n_in,
                              void* d_out, int out_size, void* d_ws, size_t ws_size,
                              hipStream_t stream) {
    const float* h   = (const float*)d_in[0];
    const int*   adj = (const int*)d_in[1];
    const float* W   = (const float*)d_in[2];
    const float* a   = (const float*)d_in[3];
    float* out = (float*)d_out;

    char* ws = (char*)d_ws;
    f16*      WT     = (f16*)ws;                        // 128 KB
    f16*      WhT    = (f16*)(ws + 131072);             // 4 MB
    float*    r1     = (float*)(ws + 4325376);          // 1 KB
    float*    r2     = (float*)(ws + 4326400);          // 1 KB
    float*    Wh1    = (float*)(ws + 4327424);          // 32 KB
    float*    Wh2    = (float*)(ws + 4360192);          // 32 KB
    unsigned* maxkey = (unsigned*)(ws + 4392960);       // 4 B (pad 256)
    float*    S      = (float*)(ws + 4393216);          // 32 KB
    float*    D      = (float*)(ws + 4425984);          // js_n x 8 MB

    const size_t base = 4425984;
    const size_t slab = (size_t)NN * DD * 4;
    int js_n = 1;
    if (ws_size >= base + 4 * slab) js_n = 4;
    else if (ws_size >= base + 2 * slab) js_n = 2;
    const int jrange = NN / js_n;

    hipMemsetAsync(ws + 4392960, 0, 256 + 32768, stream);
    k0_prep<<<dim3(18), dim3(256), 0, stream>>>(W, a, WT, r1, r2);
    k1_gemm<<<dim3(512), dim3(256), 0, stream>>>(h, WT, r1, r2, WhT, Wh1, Wh2, maxkey);
    k3_attn<<<dim3(js_n * 128), dim3(512), 0, stream>>>(adj, WhT, Wh1, Wh2, maxkey,
                                                        D, S, jrange);
    k4_finish<<<dim3(2048), dim3(256), 0, stream>>>(D, S, out, js_n);
}